// Round 1
// baseline (334.799 us; speedup 1.0000x reference)
//
#include <hip/hip_runtime.h>
#include <math.h>

#define B_ 8
#define N_ 2000
#define H_ 128
#define K_ 32
#define M_ (B_*N_)   // 16000
#define KTOT 384     // 3*H (in_agg | out_agg | h)
#define NC 512       // 4 gates * H, columns interleaved j = d*4+g

#define MT 64
#define NT 128
#define BK 16

__device__ __forceinline__ float sigm_(float x) {
    return 1.f / (1.f + __expf(-x));
}
__device__ __forceinline__ float tanhf_(float x) {
    return 2.f / (1.f + __expf(-2.f * x)) - 1.f;
}

// Build Wp[384][512]; column j = d*4 + g.
// rows 0..127: w_in[g][k][d]; 128..255: w_out; 256..383: u_in+u_out
__global__ void prep_kernel(const float* __restrict__ w_in,
                            const float* __restrict__ w_out,
                            const float* __restrict__ u_in,
                            const float* __restrict__ u_out,
                            float* __restrict__ Wp) {
    int k = blockIdx.x;          // 0..383
    int j = threadIdx.x;         // 0..511
    int d = j >> 2, g = j & 3;
    float v;
    if (k < 128) {
        v = w_in[(g * 128 + k) * 128 + d];
    } else if (k < 256) {
        v = w_out[(g * 128 + (k - 128)) * 128 + d];
    } else {
        int kk = k - 256;
        v = u_in[(g * 128 + kk) * 128 + d] + u_out[(g * 128 + kk) * 128 + d];
    }
    Wp[k * NC + j] = v;
}

// One block per (b,n) row; 128 threads = one per H dim.
__global__ __launch_bounds__(128)
void agg_kernel(const float* __restrict__ h,
                const int* __restrict__ in_idx,
                const float* __restrict__ in_mask,
                const int* __restrict__ out_idx,
                const float* __restrict__ out_mask,
                float* __restrict__ in_agg,
                float* __restrict__ out_agg) {
    int row = blockIdx.x;        // 0..M_-1
    int t = threadIdx.x;         // 0..127
    int b = row / N_;
    const float* hb = h + (size_t)b * N_ * H_;
    __shared__ int   s_idx[2 * K_];
    __shared__ float s_msk[2 * K_];
    if (t < K_) {
        s_idx[t] = in_idx[row * K_ + t];
        s_msk[t] = in_mask[row * K_ + t];
    } else if (t < 2 * K_) {
        int k = t - K_;
        s_idx[t] = out_idx[row * K_ + k];
        s_msk[t] = out_mask[row * K_ + k];
    }
    __syncthreads();
    float ai = 0.f, ao = 0.f;
    #pragma unroll 8
    for (int k = 0; k < K_; ++k) {
        ai += s_msk[k]      * hb[s_idx[k]      * H_ + t];
        ao += s_msk[K_ + k] * hb[s_idx[K_ + k] * H_ + t];
    }
    in_agg [row * H_ + t] = ai;
    out_agg[row * H_ + t] = ao;
}

// Tiled GEMM (M=16000, K=384, N=512) + fused LSTM gate epilogue.
// A = [in_agg | out_agg | h_src] (virtual concat along K).
__global__ __launch_bounds__(256)
void gemm_gates(const float* __restrict__ in_agg,
                const float* __restrict__ out_agg,
                const float* __restrict__ h_src,
                const float* __restrict__ Wp,
                const float* __restrict__ bias,   // (4,128) original layout
                const float* __restrict__ c_src,
                float* __restrict__ c_dst,
                float* __restrict__ h_dst) {
    __shared__ float As[BK][MT];
    __shared__ float Ws[BK][NT];

    int tid = threadIdx.x;
    int mt = blockIdx.x;   // 0..249
    int jt = blockIdx.y;   // 0..3
    int tx = tid & 15;     // j0 = tx*8
    int ty = tid >> 4;     // m0 = ty*4
    int row0 = mt * MT;

    float acc[4][8];
    #pragma unroll
    for (int r = 0; r < 4; ++r)
        #pragma unroll
        for (int c = 0; c < 8; ++c) acc[r][c] = 0.f;

    // staging assignments
    int am = tid >> 2;            // 0..63 : row within tile
    int ak = (tid & 3) * 4;       // 0,4,8,12 : float4 k-offset within BK
    int wk = tid >> 5;            // 0..7
    int wj = (tid & 31) * 4;      // 0..124

    for (int k0 = 0; k0 < KTOT; k0 += BK) {
        // global loads (issued before barrier for latency overlap)
        int kk = k0 + ak;
        float4 a4;
        if (kk < 128) {
            a4 = *(const float4*)&in_agg[(size_t)(row0 + am) * H_ + kk];
        } else if (kk < 256) {
            a4 = *(const float4*)&out_agg[(size_t)(row0 + am) * H_ + (kk - 128)];
        } else {
            a4 = *(const float4*)&h_src[(size_t)(row0 + am) * H_ + (kk - 256)];
        }
        float4 w4a = *(const float4*)&Wp[(size_t)(k0 + wk)     * NC + jt * NT + wj];
        float4 w4b = *(const float4*)&Wp[(size_t)(k0 + wk + 8) * NC + jt * NT + wj];

        __syncthreads();   // previous iteration's LDS reads complete
        As[ak + 0][am] = a4.x;
        As[ak + 1][am] = a4.y;
        As[ak + 2][am] = a4.z;
        As[ak + 3][am] = a4.w;
        *(float4*)&Ws[wk][wj]     = w4a;
        *(float4*)&Ws[wk + 8][wj] = w4b;
        __syncthreads();

        #pragma unroll
        for (int k2 = 0; k2 < BK; ++k2) {
            float4 a  = *(const float4*)&As[k2][ty * 4];
            float4 wA = *(const float4*)&Ws[k2][tx * 8];
            float4 wB = *(const float4*)&Ws[k2][tx * 8 + 4];
            float av[4] = {a.x, a.y, a.z, a.w};
            float wv[8] = {wA.x, wA.y, wA.z, wA.w, wB.x, wB.y, wB.z, wB.w};
            #pragma unroll
            for (int r = 0; r < 4; ++r)
                #pragma unroll
                for (int c = 0; c < 8; ++c)
                    acc[r][c] += av[r] * wv[c];
        }
    }

    // epilogue: cols of this thread = 2 d-values x 4 gates
    int dbase = jt * 32 + tx * 2;
    #pragma unroll
    for (int r = 0; r < 4; ++r) {
        int row = row0 + ty * 4 + r;
        #pragma unroll
        for (int dd = 0; dd < 2; ++dd) {
            int d = dbase + dd;
            float pi = acc[r][dd * 4 + 0] + bias[0 * H_ + d];
            float po = acc[r][dd * 4 + 1] + bias[1 * H_ + d];
            float pf = acc[r][dd * 4 + 2] + bias[2 * H_ + d];
            float pg = acc[r][dd * 4 + 3] + bias[3 * H_ + d];
            float ig = sigm_(pi);
            float og = sigm_(po);
            float fg = sigm_(pf);
            float gg = tanhf_(pg);
            float c_old = c_src[(size_t)row * H_ + d];
            float c_new = fg * c_old + ig * gg;
            c_dst[(size_t)row * H_ + d] = c_new;
            h_dst[(size_t)row * H_ + d] = og * tanhf_(c_new);
        }
    }
}

extern "C" void kernel_launch(void* const* d_in, const int* in_sizes, int n_in,
                              void* d_out, int out_size, void* d_ws, size_t ws_size,
                              hipStream_t stream) {
    const float* node_hidden = (const float*)d_in[0];
    const float* cell        = (const float*)d_in[1];
    const float* w_in        = (const float*)d_in[2];
    const float* w_out       = (const float*)d_in[3];
    const float* u_in        = (const float*)d_in[4];
    const float* u_out       = (const float*)d_in[5];
    const float* bias        = (const float*)d_in[6];
    const float* in_mask     = (const float*)d_in[7];
    const float* out_mask    = (const float*)d_in[8];
    const int*   in_idx      = (const int*)d_in[9];
    const int*   out_idx     = (const int*)d_in[10];
    // layer_num fixed at 2 by setup_inputs
    float* out = (float*)d_out;

    float* ws = (float*)d_ws;
    float* Wp      = ws;                       // 384*512   = 196608 floats
    float* in_agg  = Wp + (size_t)KTOT * NC;   // 16000*128 = 2048000
    float* out_agg = in_agg + (size_t)M_ * H_;
    float* c_buf   = out_agg + (size_t)M_ * H_;
    float* h_buf   = c_buf + (size_t)M_ * H_;  // total 32 MiB

    prep_kernel<<<KTOT, NC, 0, stream>>>(w_in, w_out, u_in, u_out, Wp);

    // layer 0: h = node_hidden -> h_buf ; c = cell -> c_buf
    agg_kernel<<<M_, 128, 0, stream>>>(node_hidden, in_idx, in_mask,
                                       out_idx, out_mask, in_agg, out_agg);
    gemm_gates<<<dim3(M_ / MT, NC / NT), 256, 0, stream>>>(
        in_agg, out_agg, node_hidden, Wp, bias, cell, c_buf, h_buf);

    // layer 1: h = h_buf -> d_out ; c = c_buf -> c_buf
    agg_kernel<<<M_, 128, 0, stream>>>(h_buf, in_idx, in_mask,
                                       out_idx, out_mask, in_agg, out_agg);
    gemm_gates<<<dim3(M_ / MT, NC / NT), 256, 0, stream>>>(
        in_agg, out_agg, h_buf, Wp, bias, c_buf, c_buf, out);
}

// Round 2
// 205.788 us; speedup vs baseline: 1.6269x; 1.6269x over previous
//
#include <hip/hip_runtime.h>
#include <math.h>

#define B_ 8
#define N_ 2000
#define H_ 128
#define K_ 32
#define M_ (B_*N_)    // 16000
#define KTOT 384      // h-index: [in_agg | out_agg | h]
#define NC 512        // columns j = d*4 + g  (g: i,o,f,cell)

typedef __attribute__((ext_vector_type(8))) short s8_t;
typedef __attribute__((ext_vector_type(4))) float f4_t;

__device__ __forceinline__ unsigned short f2bf(float x) {
    union { float f; unsigned u; } v; v.f = x;
    unsigned r = v.u + 0x7fff + ((v.u >> 16) & 1);   // RN-even
    return (unsigned short)(r >> 16);
}
__device__ __forceinline__ float bf2f(unsigned short b) {
    union { unsigned u; float f; } v; v.u = (unsigned)b << 16; return v.f;
}
__device__ __forceinline__ float sigm_(float x) { return 1.f / (1.f + __expf(-x)); }
__device__ __forceinline__ float tanh_(float x) { return 2.f / (1.f + __expf(-2.f * x)) - 1.f; }

__device__ __forceinline__ float pickv(f4_t A, int m) {
    float ab = (m & 1) ? A.y : A.x;
    float cd = (m & 1) ? A.w : A.z;
    return (m & 2) ? cd : ab;
}
__device__ __forceinline__ float pick4(float u0, float u1, float u2, float u3, int m) {
    float ab = (m & 1) ? u1 : u0;
    float cd = (m & 1) ? u3 : u2;
    return (m & 2) ? cd : ab;
}

// pack 8 floats -> 8 bf16 hi + 8 bf16 lo (as uint4 each)
__device__ __forceinline__ void cvt8(float4 a, float4 b, uint4& hi, uint4& lo) {
    float f[8] = {a.x, a.y, a.z, a.w, b.x, b.y, b.z, b.w};
    unsigned h[8], l[8];
    #pragma unroll
    for (int i = 0; i < 8; ++i) {
        unsigned short hs = f2bf(f[i]);
        h[i] = hs;
        l[i] = f2bf(f[i] - bf2f(hs));
    }
    hi.x = h[0] | (h[1] << 16); hi.y = h[2] | (h[3] << 16);
    hi.z = h[4] | (h[5] << 16); hi.w = h[6] | (h[7] << 16);
    lo.x = l[0] | (l[1] << 16); lo.y = l[2] | (l[3] << 16);
    lo.z = l[4] | (l[5] << 16); lo.w = l[6] | (l[7] << 16);
}

// Wp[j][k], j = d*4+g (512 rows), k = 0..383; split bf16 hi/lo planes.
__global__ void prep_kernel(const float* __restrict__ w_in,
                            const float* __restrict__ w_out,
                            const float* __restrict__ u_in,
                            const float* __restrict__ u_out,
                            unsigned short* __restrict__ wp_hi,
                            unsigned short* __restrict__ wp_lo) {
    int j = blockIdx.x;          // 0..511
    int k = threadIdx.x;         // 0..383
    int d = j >> 2, g = j & 3;
    float v;
    if (k < 128) {
        v = w_in[(g * 128 + k) * 128 + d];
    } else if (k < 256) {
        v = w_out[(g * 128 + (k - 128)) * 128 + d];
    } else {
        int kk = k - 256;
        v = u_in[(g * 128 + kk) * 128 + d] + u_out[(g * 128 + kk) * 128 + d];
    }
    unsigned short hs = f2bf(v);
    wp_hi[(size_t)j * KTOT + k] = hs;
    wp_lo[(size_t)j * KTOT + k] = f2bf(v - bf2f(hs));
}

// 8 rows per block, 32 lanes (float4) per row. Outputs split-bf16 A rows:
// agg_hi/lo[row][0..127] = in_agg, [128..255] = out_agg.
__global__ __launch_bounds__(256)
void agg_kernel(const float* __restrict__ h,
                const int* __restrict__ in_idx,
                const float* __restrict__ in_mask,
                const int* __restrict__ out_idx,
                const float* __restrict__ out_mask,
                unsigned short* __restrict__ agg_hi,
                unsigned short* __restrict__ agg_lo) {
    int tid = threadIdx.x;
    int r = tid >> 5;            // 0..7
    int t = tid & 31;            // 0..31
    int row = blockIdx.x * 8 + r;
    int b = row / N_;
    const float* hb = h + (size_t)b * N_ * H_;

    __shared__ int   s_idx[8][64];
    __shared__ float s_msk[8][64];
    for (int e = tid; e < 512; e += 256) {
        int r2 = e >> 6, q = e & 63;
        int ridx = blockIdx.x * 8 + r2;
        if (q < 32) {
            s_idx[r2][q] = in_idx[ridx * K_ + q];
            s_msk[r2][q] = in_mask[ridx * K_ + q];
        } else {
            s_idx[r2][q] = out_idx[ridx * K_ + (q - 32)];
            s_msk[r2][q] = out_mask[ridx * K_ + (q - 32)];
        }
    }
    __syncthreads();

    float ax = 0.f, ay = 0.f, az = 0.f, aw = 0.f;
    float ox = 0.f, oy = 0.f, oz = 0.f, ow = 0.f;
    #pragma unroll 4
    for (int k = 0; k < K_; ++k) {
        int   i1 = s_idx[r][k];
        float m1 = s_msk[r][k];
        float4 v1 = *(const float4*)(hb + (size_t)i1 * H_ + t * 4);
        int   i2 = s_idx[r][32 + k];
        float m2 = s_msk[r][32 + k];
        float4 v2 = *(const float4*)(hb + (size_t)i2 * H_ + t * 4);
        ax += m1 * v1.x; ay += m1 * v1.y; az += m1 * v1.z; aw += m1 * v1.w;
        ox += m2 * v2.x; oy += m2 * v2.y; oz += m2 * v2.z; ow += m2 * v2.w;
    }

    float fi[4] = {ax, ay, az, aw};
    float fo[4] = {ox, oy, oz, ow};
    unsigned short hi_i[4], lo_i[4], hi_o[4], lo_o[4];
    #pragma unroll
    for (int q = 0; q < 4; ++q) {
        hi_i[q] = f2bf(fi[q]); lo_i[q] = f2bf(fi[q] - bf2f(hi_i[q]));
        hi_o[q] = f2bf(fo[q]); lo_o[q] = f2bf(fo[q] - bf2f(hi_o[q]));
    }
    size_t base = (size_t)row * 256;
    *(ushort4*)(agg_hi + base + t * 4)       = make_ushort4(hi_i[0], hi_i[1], hi_i[2], hi_i[3]);
    *(ushort4*)(agg_lo + base + t * 4)       = make_ushort4(lo_i[0], lo_i[1], lo_i[2], lo_i[3]);
    *(ushort4*)(agg_hi + base + 128 + t * 4) = make_ushort4(hi_o[0], hi_o[1], hi_o[2], hi_o[3]);
    *(ushort4*)(agg_lo + base + 128 + t * 4) = make_ushort4(lo_o[0], lo_o[1], lo_o[2], lo_o[3]);
}

// 128x128 tile MFMA GEMM (K=384) with split-bf16 (3 passes) + fused LSTM gates.
__global__ __launch_bounds__(256)
void gemm_gates(const unsigned short* __restrict__ agg_hi,
                const unsigned short* __restrict__ agg_lo,
                const float* __restrict__ h_src,
                const unsigned short* __restrict__ wp_hi,
                const unsigned short* __restrict__ wp_lo,
                const float* __restrict__ bias,
                const float* __restrict__ c_src,
                float* __restrict__ c_dst,
                float* __restrict__ h_dst) {
    __shared__ short As_hi[128 * 32];
    __shared__ short As_lo[128 * 32];
    __shared__ short Ws_hi[128 * 32];
    __shared__ short Ws_lo[128 * 32];

    int tid  = threadIdx.x;
    int mt   = blockIdx.x;       // 0..124
    int jt   = blockIdx.y;       // 0..3
    int row0 = mt * 128;
    int lane = tid & 63;
    int wave = tid >> 6;
    int m_off = (wave & 1) * 64;
    int n_off = (wave >> 1) * 64;
    int ml = lane & 15;
    int kg = lane >> 4;          // 0..3

    f4_t zero = {0.f, 0.f, 0.f, 0.f};
    f4_t acc[4][4];
    #pragma unroll
    for (int i = 0; i < 4; ++i)
        #pragma unroll
        for (int j = 0; j < 4; ++j) acc[i][j] = zero;

    int e0 = tid, e1 = tid + 256;
    int ar0 = e0 >> 2, ac0 = e0 & 3;
    int ar1 = e1 >> 2, ac1 = e1 & 3;

    #pragma unroll 1
    for (int k0 = 0; k0 < KTOT; k0 += 32) {
        uint4 ahi0, alo0, ahi1, alo1;
        if (k0 < 256) {
            const unsigned short* ph = agg_hi + (size_t)row0 * 256 + k0;
            const unsigned short* pl = agg_lo + (size_t)row0 * 256 + k0;
            ahi0 = *(const uint4*)(ph + ar0 * 256 + ac0 * 8);
            alo0 = *(const uint4*)(pl + ar0 * 256 + ac0 * 8);
            ahi1 = *(const uint4*)(ph + ar1 * 256 + ac1 * 8);
            alo1 = *(const uint4*)(pl + ar1 * 256 + ac1 * 8);
        } else {
            const float* pf = h_src + (size_t)row0 * 128 + (k0 - 256);
            float4 f0a = *(const float4*)(pf + ar0 * 128 + ac0 * 8);
            float4 f0b = *(const float4*)(pf + ar0 * 128 + ac0 * 8 + 4);
            float4 f1a = *(const float4*)(pf + ar1 * 128 + ac1 * 8);
            float4 f1b = *(const float4*)(pf + ar1 * 128 + ac1 * 8 + 4);
            cvt8(f0a, f0b, ahi0, alo0);
            cvt8(f1a, f1b, ahi1, alo1);
        }
        const unsigned short* pwh = wp_hi + (size_t)(jt * 128) * KTOT + k0;
        const unsigned short* pwl = wp_lo + (size_t)(jt * 128) * KTOT + k0;
        uint4 whi0 = *(const uint4*)(pwh + ar0 * KTOT + ac0 * 8);
        uint4 wlo0 = *(const uint4*)(pwl + ar0 * KTOT + ac0 * 8);
        uint4 whi1 = *(const uint4*)(pwh + ar1 * KTOT + ac1 * 8);
        uint4 wlo1 = *(const uint4*)(pwl + ar1 * KTOT + ac1 * 8);

        __syncthreads();
        *(uint4*)&As_hi[e0 * 8] = ahi0;
        *(uint4*)&As_hi[e1 * 8] = ahi1;
        *(uint4*)&As_lo[e0 * 8] = alo0;
        *(uint4*)&As_lo[e1 * 8] = alo1;
        *(uint4*)&Ws_hi[e0 * 8] = whi0;
        *(uint4*)&Ws_hi[e1 * 8] = whi1;
        *(uint4*)&Ws_lo[e0 * 8] = wlo0;
        *(uint4*)&Ws_lo[e1 * 8] = wlo1;
        __syncthreads();

        s8_t a_hi[4], a_lo[4], b_hi[4], b_lo[4];
        #pragma unroll
        for (int i = 0; i < 4; ++i) {
            int m = m_off + i * 16 + ml;
            a_hi[i] = *(const s8_t*)&As_hi[m * 32 + kg * 8];
            a_lo[i] = *(const s8_t*)&As_lo[m * 32 + kg * 8];
        }
        #pragma unroll
        for (int j = 0; j < 4; ++j) {
            int n = n_off + j * 16 + ml;
            b_hi[j] = *(const s8_t*)&Ws_hi[n * 32 + kg * 8];
            b_lo[j] = *(const s8_t*)&Ws_lo[n * 32 + kg * 8];
        }
        #pragma unroll
        for (int i = 0; i < 4; ++i)
            #pragma unroll
            for (int j = 0; j < 4; ++j) {
                acc[i][j] = __builtin_amdgcn_mfma_f32_16x16x32_bf16(a_hi[i], b_hi[j], acc[i][j], 0, 0, 0);
                acc[i][j] = __builtin_amdgcn_mfma_f32_16x16x32_bf16(a_hi[i], b_lo[j], acc[i][j], 0, 0, 0);
                acc[i][j] = __builtin_amdgcn_mfma_f32_16x16x32_bf16(a_lo[i], b_hi[j], acc[i][j], 0, 0, 0);
            }
    }

    // Epilogue. C layout: col = lane&15, row = (lane>>4)*4 + reg.
    // Quad (4 adjacent lanes) shares d; lane's gate g = lane&3.
    // Each lane finalizes reg r = g -> all 64 lanes produce unique (row,d).
    int g    = lane & 3;
    int qrow = lane >> 4;        // 0..3
    int dl   = (lane >> 2) & 3;  // d sub-index in 16-col tile
    #pragma unroll
    for (int j = 0; j < 4; ++j) {
        int ncol_base = jt * 128 + n_off + j * 16;
        int d = (ncol_base >> 2) + dl;
        float b0 = bias[0 * 128 + d];
        float b1 = bias[1 * 128 + d];
        float b2 = bias[2 * 128 + d];
        float b3 = bias[3 * 128 + d];
        #pragma unroll
        for (int i = 0; i < 4; ++i) {
            f4_t A = acc[i][j];
            // s_m = own acc[reg g^m]; u_m = shfl_xor(s_m, m) = (reg g, gate g^m)
            float s0 = pickv(A, g);
            float s1 = pickv(A, g ^ 1);
            float s2 = pickv(A, g ^ 2);
            float s3 = pickv(A, g ^ 3);
            float u0 = s0;
            float u1 = __shfl_xor(s1, 1);
            float u2 = __shfl_xor(s2, 2);
            float u3 = __shfl_xor(s3, 3);
            // pre[t] = u_{g^t}
            float p0 = pick4(u0, u1, u2, u3, g) + b0;
            float p1 = pick4(u0, u1, u2, u3, g ^ 1) + b1;
            float p2 = pick4(u0, u1, u2, u3, g ^ 2) + b2;
            float p3 = pick4(u0, u1, u2, u3, g ^ 3) + b3;
            float ig = sigm_(p0);
            float og = sigm_(p1);
            float fg = sigm_(p2);
            float cg = tanh_(p3);
            int row = row0 + m_off + i * 16 + qrow * 4 + g;
            size_t off = (size_t)row * H_ + d;
            float c_old = c_src[off];
            float c_new = fg * c_old + ig * cg;
            c_dst[off] = c_new;
            h_dst[off] = og * tanh_(c_new);
        }
    }
}

extern "C" void kernel_launch(void* const* d_in, const int* in_sizes, int n_in,
                              void* d_out, int out_size, void* d_ws, size_t ws_size,
                              hipStream_t stream) {
    const float* node_hidden = (const float*)d_in[0];
    const float* cell        = (const float*)d_in[1];
    const float* w_in        = (const float*)d_in[2];
    const float* w_out       = (const float*)d_in[3];
    const float* u_in        = (const float*)d_in[4];
    const float* u_out       = (const float*)d_in[5];
    const float* bias        = (const float*)d_in[6];
    const float* in_mask     = (const float*)d_in[7];
    const float* out_mask    = (const float*)d_in[8];
    const int*   in_idx      = (const int*)d_in[9];
    const int*   out_idx     = (const int*)d_in[10];
    float* out = (float*)d_out;

    char* p = (char*)d_ws;
    unsigned short* wp_hi  = (unsigned short*)p;                     p += (size_t)NC * KTOT * 2;  // 384 KB
    unsigned short* wp_lo  = (unsigned short*)p;                     p += (size_t)NC * KTOT * 2;
    unsigned short* agg_hi = (unsigned short*)p;                     p += (size_t)M_ * 256 * 2;   // 8 MB
    unsigned short* agg_lo = (unsigned short*)p;                     p += (size_t)M_ * 256 * 2;
    float* h_buf = (float*)p;                                        p += (size_t)M_ * H_ * 4;
    float* c_buf = (float*)p;                                        p += (size_t)M_ * H_ * 4;    // total 32 MiB

    prep_kernel<<<NC, KTOT, 0, stream>>>(w_in, w_out, u_in, u_out, wp_hi, wp_lo);

    // layer 0
    agg_kernel<<<M_ / 8, 256, 0, stream>>>(node_hidden, in_idx, in_mask,
                                           out_idx, out_mask, agg_hi, agg_lo);
    gemm_gates<<<dim3(M_ / 128, 4), 256, 0, stream>>>(
        agg_hi, agg_lo, node_hidden, wp_hi, wp_lo, bias, cell, c_buf, h_buf);

    // layer 1
    agg_kernel<<<M_ / 8, 256, 0, stream>>>(h_buf, in_idx, in_mask,
                                           out_idx, out_mask, agg_hi, agg_lo);
    gemm_gates<<<dim3(M_ / 128, 4), 256, 0, stream>>>(
        agg_hi, agg_lo, h_buf, wp_hi, wp_lo, bias, c_buf, c_buf, out);
}